// Round 7
// baseline (235.999 us; speedup 1.0000x reference)
//
#include <hip/hip_runtime.h>

#define BB 4
#define SQn 2048
#define SS 2048
#define DM 256
#define DH 32

typedef unsigned short u16;
typedef unsigned int u32;
typedef _Float16 f16;
typedef __attribute__((ext_vector_type(8))) f16 f16x8;
typedef __attribute__((ext_vector_type(8))) short s16x8;
typedef __attribute__((ext_vector_type(4))) float f32x4;
typedef __attribute__((ext_vector_type(2))) float f32x2;
typedef __attribute__((ext_vector_type(4))) u32 u32x4;
typedef __attribute__((ext_vector_type(2))) u32 u32x2;

__device__ __forceinline__ float bf2f(u16 x){ u32 u=((u32)x)<<16; return __builtin_bit_cast(float,u); }
__device__ __forceinline__ u16 f2bf(float f){ u32 u=__builtin_bit_cast(u32,f); u32 r=(u+0x7fffu+((u>>16)&1u))>>16; return (u16)r; }

// Load 8 consecutive elements as f16 from bf16 (fl=0) or fp32 (fl=1) buffer.
__device__ __forceinline__ f16x8 ld8(const void* p, size_t off, int fl)
{
    f16x8 r;
    if (fl) {
        const float* f = (const float*)p + off;
        f32x4 a = *(const f32x4*)f;
        f32x4 b = *(const f32x4*)(f + 4);
        #pragma unroll
        for (int i = 0; i < 4; ++i) { r[i] = (f16)a[i]; r[4+i] = (f16)b[i]; }
    } else {
        const u16* s = (const u16*)p + off;
        u32x4 v = *(const u32x4*)s;
        #pragma unroll
        for (int i = 0; i < 4; ++i) {
            u32 x = v[i];
            r[2*i]   = (f16)bf2f((u16)(x & 0xffff));
            r[2*i+1] = (f16)bf2f((u16)(x >> 16));
        }
    }
    return r;
}
__device__ __forceinline__ float ld1(const void* p, int idx, int fl)
{ return fl ? ((const float*)p)[idx] : bf2f(((const u16*)p)[idx]); }

// ---------------------------------------------------------------------------
// Dtype detection: 0 = bf16 inputs, 1 = fp32 inputs.
// ---------------------------------------------------------------------------
__global__ void detect_kernel(const u32* __restrict__ q, int* __restrict__ flag)
{
    int t = threadIdx.x;                 // 256
    u32 w = q[t];
    u32 e = (w >> 7) & 0xFFu;
    int vote = ((e >= 0x70u && e <= 0x85u) || ((w & 0xFFFFu) == 0u)) ? 1 : 0;
    #pragma unroll
    for (int d = 1; d < 64; d <<= 1) vote += __shfl_xor(vote, d);
    __shared__ int ps[4];
    if ((t & 63) == 0) ps[t >> 6] = vote;
    __syncthreads();
    if (t == 0) *flag = ((ps[0]+ps[1]+ps[2]+ps[3]) >= 128) ? 0 : 1;
}

// ---------------------------------------------------------------------------
// Kernel A: fused projections (f16 MFMA).
//   q -> qf f16 [s][256]
//   k -> kf2 f16 [h][s][32]                   (per-head contiguous: coalesced bk)
//   v -> vt2 bf16 [b][h][kt][nt][quad][l15][8] (MFMA-fragment order: coalesced bv)
// ---------------------------------------------------------------------------
__global__ __launch_bounds__(256) void proj_kernel(
    const int* __restrict__ flag,
    const void* __restrict__ query, const void* __restrict__ values, const void* __restrict__ tkeys,
    const void* __restrict__ Wq, const void* __restrict__ Wqb,
    const void* __restrict__ Wk, const void* __restrict__ Wkb,
    const void* __restrict__ Wv, const void* __restrict__ Wvb,
    f16* __restrict__ qf, f16* __restrict__ kf, u16* __restrict__ vt)
{
    int fl = *flag;
    int bx = blockIdx.x;
    const void *X, *W, *Bi; int mode, rowbase;
    if (bx < 128)      { X=query;  W=Wq; Bi=Wqb; mode=0; rowbase=bx*64; }
    else if (bx < 256) { X=values; W=Wv; Bi=Wvb; mode=2; rowbase=(bx-128)*64; }
    else               { X=tkeys;  W=Wk; Bi=Wkb; mode=1; rowbase=(bx-256)*64; }
    int colbase = blockIdx.y * 64;

    __shared__ f16 Xs[64][40];
    __shared__ f16 Ws[64][40];
    __shared__ u16 Os[64][72];

    int t = threadIdx.x;
    int lane = t & 63, w = t >> 6;
    int quad = lane >> 4, l15 = lane & 15;

    const f32x4 fz = {0.f,0.f,0.f,0.f};
    f32x4 acc[4] = {fz,fz,fz,fz};

    for (int ks = 0; ks < 8; ++ks) {
        int k0 = ks * 32;
        {
            int row = t >> 2, ch = (t & 3) * 8;
            f16x8 xv = ld8(X, (size_t)(rowbase+row)*DM + k0 + ch, fl);
            f16x8 wv = ld8(W, (size_t)(colbase+row)*DM + k0 + ch, fl);
            *(f16x8*)(&Xs[row][ch]) = xv;
            *(f16x8*)(&Ws[row][ch]) = wv;
        }
        __syncthreads();
        f16x8 a = *(const f16x8*)(&Xs[w*16 + l15][quad*8]);
        #pragma unroll
        for (int nt = 0; nt < 4; ++nt) {
            f16x8 bfr = *(const f16x8*)(&Ws[nt*16 + l15][quad*8]);
            acc[nt] = __builtin_amdgcn_mfma_f32_16x16x32_f16(a, bfr, acc[nt], 0, 0, 0);
        }
        __syncthreads();
    }

    if (mode == 2) {
        // vt2 fragment-interleaved store
        int m = rowbase + w*16 + quad*4;     // 4 consecutive seq positions
        int bb = m >> 11, s = m & 2047;
        int ktv = s >> 5, qv = (s >> 3) & 3, kk = s & 7;   // kk in {0,4}
        #pragma unroll
        for (int nt = 0; nt < 4; ++nt) {
            int col = colbase + nt*16 + l15;
            float bv = ld1(Bi, col, fl);
            int hv = col >> 5, ntv = (col >> 4) & 1;
            size_t idx = (((((size_t)(bb*8 + hv))*64 + ktv)*2 + ntv)*4 + qv)*128
                         + (size_t)(col & 15)*8 + kk;
            u32x2 pk;
            pk[0] = (u32)f2bf(acc[nt][0]+bv) | ((u32)f2bf(acc[nt][1]+bv) << 16);
            pk[1] = (u32)f2bf(acc[nt][2]+bv) | ((u32)f2bf(acc[nt][3]+bv) << 16);
            *(u32x2*)(vt + idx) = pk;
        }
    } else {
        #pragma unroll
        for (int nt = 0; nt < 4; ++nt) {
            int col = nt*16 + l15;
            float bv = ld1(Bi, colbase + col, fl);
            #pragma unroll
            for (int r = 0; r < 4; ++r)
                Os[w*16 + quad*4 + r][col] = __builtin_bit_cast(u16, (f16)(acc[nt][r] + bv));
        }
        __syncthreads();
        #pragma unroll
        for (int p = 0; p < 2; ++p) {
            int rr = (t >> 3) + p*32;
            int ch = (t & 7) * 8;
            u32x4 v = *(const u32x4*)(&Os[rr][ch]);
            if (mode == 0) {
                *(u32x4*)(qf + (size_t)(rowbase+rr)*DM + colbase + ch) = v;
            } else {
                int head = (colbase + ch) >> 5;
                int dh = ch & 31;
                *(u32x4*)(kf + (size_t)head*(SS*DH) + (size_t)(rowbase+rr)*DH + dh) = v;
            }
        }
    }
}

// ---------------------------------------------------------------------------
// Kernel B: per row q: rs = (1/sqrt(32)) / sum_k 1/(d+eps)  (precise-div sum,
// identical to before), then write dwv = rs * rcpf(d+eps) -- the EXACT value
// attn previously computed per-element -- into distT in MFMA-fragment tile
// order: distT[((b*64+qt)*64+kt)*1024 + (mt*2+nt)*256 + lane*4 + r].
// ---------------------------------------------------------------------------
__global__ __launch_bounds__(256) void dwsum_kernel(
    const int* __restrict__ flag, const void* __restrict__ dist, float* __restrict__ distT)
{
    int fl = *flag;
    int row = blockIdx.x;                // b*2048 + q
    int t = threadIdx.x;

    float d[8];
    if (fl) {
        const float* p = (const float*)dist + (size_t)row * SS + t*8;
        f32x4 a = *(const f32x4*)p;
        f32x4 b4 = *(const f32x4*)(p + 4);
        #pragma unroll
        for (int i = 0; i < 4; ++i) { d[i] = a[i]; d[4+i] = b4[i]; }
    } else {
        const u16* p = (const u16*)dist + (size_t)row * SS + t*8;
        u32x4 v = *(const u32x4*)p;
        #pragma unroll
        for (int i = 0; i < 4; ++i) {
            u32 x = v[i];
            d[2*i]   = bf2f((u16)(x & 0xffff));
            d[2*i+1] = bf2f((u16)(x >> 16));
        }
    }
    float s = 0.f;
    #pragma unroll
    for (int i = 0; i < 8; ++i) s += 1.0f / (d[i] + 1e-9f);
    #pragma unroll
    for (int dd = 1; dd < 64; dd <<= 1) s += __shfl_xor(s, dd);
    __shared__ float ps[4];
    __shared__ float srs;
    if ((t & 63) == 0) ps[t >> 6] = s;
    __syncthreads();
    if (t == 0) srs = 0.17677669529663687f / (ps[0] + ps[1] + ps[2] + ps[3]);
    __syncthreads();
    float rs = srs;

    int b = row >> 11, q = row & 2047;
    int qt = q >> 5, mt = (q >> 4) & 1, l15 = q & 15;
    #pragma unroll
    for (int c = 0; c < 2; ++c) {
        int k = t*8 + c*4;
        int kt = k >> 5, nt = (k >> 4) & 1, quad = (k >> 2) & 3;
        f32x4 wv;
        #pragma unroll
        for (int r = 0; r < 4; ++r)
            wv[r] = rs * __builtin_amdgcn_rcpf(d[c*4 + r] + 1e-9f);
        size_t idx = ((size_t)((b*64 + qt)*64 + kt))*1024
                     + (mt*2 + nt)*256 + (quad*16 + l15)*4;
        *(f32x4*)(distT + idx) = wv;
    }
}

// ---------------------------------------------------------------------------
// Kernel C: flash attention (no-max softmax, S^T orientation) + fused fc.
// 1 block = (b, 32 q-rows), 16 waves = 8 heads x 2 k-halves.  dist weights are
// PRECOMPUTED (dwv in distT, fragment-tiled): softmax is just exp(st*dwv) --
// no rcp/add in the loop -- and the LDS staging of dwv is a linear copy, so
// both the staging write and the fragment read are bank-conflict-free.
// ---------------------------------------------------------------------------
#define LDP 40
#define LDO 264
#define DB_OFF 40960
#define OL_OFF  49152
#define OUTF_OFF 66048

__global__ __launch_bounds__(1024) void attn_kernel(
    const int* __restrict__ flag,
    const float* __restrict__ distT,
    const f16* __restrict__ qf, const f16* __restrict__ kf, const u16* __restrict__ vtg,
    const void* __restrict__ fcw, const void* __restrict__ fcb,
    void* __restrict__ out)
{
    __shared__ __align__(16) char smem[99840];
    // loop:   P slices [16][32][LDP] u16 at 0 (40960);
    //         dwv dbuf 4x1024 f32 at 40960 (16384): buf (phase*2+group), linear tiles
    // combine: Cx f32 [512][24] at 0 (49152)
    // epilog:  Ol f16 [32][LDO] at 49152 (16896); OutF f32 [32][LDO] at 66048 (33792)

    int fl = *flag;
    int t = threadIdx.x;
    int w = t >> 6, lane = t & 63;
    int quad = lane >> 4, l15 = lane & 15;
    int b = blockIdx.y, q0 = blockIdx.x * 32;
    int h = w & 7, khalf = w >> 3;

    u16* Pw = (u16*)(smem + w * 2560);
    float* dbB = (float*)(smem + DB_OFF);

    f16x8 aq[2];
    #pragma unroll
    for (int mt = 0; mt < 2; ++mt)
        aq[mt] = *(const f16x8*)(qf + (size_t)(b*SQn + q0 + mt*16 + l15)*DM + h*DH + quad*8);

    // ones-column B-fragment (bf16): B[k][0]=1, else 0 -> row-sum via MFMA
    u32 ov = (l15 == 0) ? 0x3F803F80u : 0u;
    u32x4 ovv = {ov, ov, ov, ov};
    s16x8 ones = __builtin_bit_cast(s16x8, ovv);

    const f32x4 fz = {0.f,0.f,0.f,0.f};
    f32x4 o[2][2] = {{fz,fz},{fz,fz}};
    f32x4 lacc[2] = {fz, fz};

    const f16* kfh = kf + (size_t)h * (SS*DH);
    const u16* vth = vtg + (((size_t)(b*8 + h)) << 16);   // * 64 kt * 1024 u16
    const float* dTb = distT + ((size_t)(b*64 + blockIdx.x))*64*1024;

    // dwv staging: thread group g (== its waves' khalf) stages that group's tile
    int g  = t >> 9;
    int tt = t & 511;

    // ---- prologue: stage dwv tile 0 (both groups); load K/V tile 0 ----
    {
        f32x2 sv = *(const f32x2*)(dTb + (size_t)(g*32)*1024 + tt*2);
        float* d0 = dbB + g*1024;
        *(f32x2*)(d0 + tt*2) = sv;
    }
    f16x8 ck[2]; s16x8 cv[2];
    {
        int ktg0 = khalf * 32;
        #pragma unroll
        for (int nt = 0; nt < 2; ++nt) {
            ck[nt] = *(const f16x8*)(kfh + (size_t)(ktg0*32 + nt*16 + l15)*DH + quad*8);
            cv[nt] = __builtin_bit_cast(s16x8,
                *(const u32x4*)(vth + (size_t)ktg0*1024 + nt*512 + quad*128 + l15*8));
        }
    }
    __syncthreads();

    for (int kt = 0; kt < 32; ++kt) {
        int ktn  = (kt + 1) & 31;                // wrap: last prefetch reads valid memory
        int ktgn = khalf*32 + ktn;

        // issue next-tile loads early (hide under compute; barrier drains them)
        f32x2 sv = *(const f32x2*)(dTb + (size_t)(g*32 + ktn)*1024 + tt*2);
        f16x8 nk[2]; s16x8 nv[2];
        #pragma unroll
        for (int nt = 0; nt < 2; ++nt) {
            nk[nt] = *(const f16x8*)(kfh + (size_t)(ktgn*32 + nt*16 + l15)*DH + quad*8);
            nv[nt] = __builtin_bit_cast(s16x8,
                *(const u32x4*)(vth + (size_t)ktgn*1024 + nt*512 + quad*128 + l15*8));
        }

        // dwv fragment from LDS (linear per lane: conflict-free)
        const float* dbc = dbB + ((kt & 1)*2 + khalf)*1024;
        f32x4 dd[2][2];
        #pragma unroll
        for (int mt = 0; mt < 2; ++mt)
            #pragma unroll
            for (int nt = 0; nt < 2; ++nt)
                dd[mt][nt] = *(const f32x4*)(dbc + (mt*2 + nt)*256 + lane*4);

        // S^T = K·Q^T : C elem (key = nt*16+quad*4+r, q = mt*16+l15)
        f32x4 st[2][2];
        #pragma unroll
        for (int mt = 0; mt < 2; ++mt)
            #pragma unroll
            for (int nt = 0; nt < 2; ++nt)
                st[mt][nt] = __builtin_amdgcn_mfma_f32_16x16x32_f16(ck[nt], aq[mt], fz, 0, 0, 0);

        // softmax-lite: p = exp(st * dwv)  (dwv precomputed; no rcp/add here)
        #pragma unroll
        for (int mt = 0; mt < 2; ++mt)
            #pragma unroll
            for (int nt = 0; nt < 2; ++nt) {
                u32 pb[4];
                #pragma unroll
                for (int r = 0; r < 4; ++r) {
                    float p = __expf(st[mt][nt][r] * dd[mt][nt][r]);
                    pb[r] = __builtin_bit_cast(u32, p);
                }
                u32x2 pk;
                pk[0] = __builtin_amdgcn_perm(pb[1], pb[0], 0x07060302u);  // [p1.hi16|p0.hi16]
                pk[1] = __builtin_amdgcn_perm(pb[3], pb[2], 0x07060302u);
                *(u32x2*)(Pw + (mt*16 + l15)*LDP + nt*16 + quad*4) = pk;
            }
        __asm__ __volatile__("" ::: "memory");   // order the per-wave LDS transpose

        // P @ [V | 1] in bf16 (l arrives in o's C-layout; same rounded p in num & denom)
        #pragma unroll
        for (int mt = 0; mt < 2; ++mt) {
            s16x8 ap = *(const s16x8*)(Pw + (mt*16 + l15)*LDP + quad*8);
            lacc[mt] = __builtin_amdgcn_mfma_f32_16x16x32_bf16(ap, ones, lacc[mt], 0, 0, 0);
            #pragma unroll
            for (int nt = 0; nt < 2; ++nt)
                o[mt][nt] = __builtin_amdgcn_mfma_f32_16x16x32_bf16(ap, cv[nt], o[mt][nt], 0, 0, 0);
        }

        // write next dwv tile into the other phase buffer; barrier publishes it
        {
            float* dbn = dbB + (((kt + 1) & 1)*2 + g)*1024;
            *(f32x2*)(dbn + tt*2) = sv;
        }
        __syncthreads();

        ck[0] = nk[0]; ck[1] = nk[1]; cv[0] = nv[0]; cv[1] = nv[1];
    }

    // ---- combine the two k-halves (plain sums: no-max softmax is linear in k) ----
    float* Cx = (float*)smem;              // [512][24] f32
    if (w >= 8) {
        float* dst = Cx + ((w - 8)*64 + lane)*24;
        *(f32x4*)(dst +  0) = o[0][0];
        *(f32x4*)(dst +  4) = o[0][1];
        *(f32x4*)(dst +  8) = o[1][0];
        *(f32x4*)(dst + 12) = o[1][1];
        *(f32x4*)(dst + 16) = lacc[0];
        *(f32x4*)(dst + 20) = lacc[1];
    }
    __syncthreads();
    f16* Ol = (f16*)(smem + OL_OFF);       // [32][LDO]
    if (w < 8) {
        const float* src = Cx + (w*64 + lane)*24;
        o[0][0] += *(const f32x4*)(src +  0);
        o[0][1] += *(const f32x4*)(src +  4);
        o[1][0] += *(const f32x4*)(src +  8);
        o[1][1] += *(const f32x4*)(src + 12);
        lacc[0] += *(const f32x4*)(src + 16);
        lacc[1] += *(const f32x4*)(src + 20);

        // normalize: l for row (mt,quad,r) lives at lane (l15=0, quad), col 0
        #pragma unroll
        for (int mt = 0; mt < 2; ++mt)
            #pragma unroll
            for (int r = 0; r < 4; ++r) {
                float lv = __shfl(lacc[mt][r], lane & 48);
                float inv = 1.0f / lv;
                o[mt][0][r] *= inv;
                o[mt][1][r] *= inv;
            }

        #pragma unroll
        for (int mt = 0; mt < 2; ++mt)
            #pragma unroll
            for (int nt = 0; nt < 2; ++nt)
                #pragma unroll
                for (int r = 0; r < 4; ++r)
                    Ol[(mt*16 + quad*4 + r)*LDO + h*DH + nt*16 + l15] = (f16)o[mt][nt][r];
    }
    __syncthreads();

    // ---- fused fc across all 16 waves: wave w owns output cols w*16..w*16+15 ----
    f32x4 c[2] = {fz, fz};
    int n = w*16 + l15;
    for (int ks = 0; ks < 8; ++ks) {
        f16x8 bw = ld8(fcw, (size_t)n*DM + ks*32 + quad*8, fl);
        #pragma unroll
        for (int mt = 0; mt < 2; ++mt) {
            f16x8 a2 = *(const f16x8*)(Ol + (mt*16 + l15)*LDO + ks*32 + quad*8);
            c[mt] = __builtin_amdgcn_mfma_f32_16x16x32_f16(a2, bw, c[mt], 0, 0, 0);
        }
    }
    float* OutF = (float*)(smem + OUTF_OFF);  // [32][LDO] f32
    {
        float bv = ld1(fcb, n, fl);
        #pragma unroll
        for (int mt = 0; mt < 2; ++mt)
            #pragma unroll
            for (int r = 0; r < 4; ++r)
                OutF[(mt*16 + quad*4 + r)*LDO + n] = c[mt][r] + bv;
    }
    __syncthreads();
    if (fl) {
        float* of = (float*)out;
        int row = t >> 5, col = (t & 31) * 8;
        f32x4 v0 = *(const f32x4*)(OutF + row*LDO + col);
        f32x4 v1 = *(const f32x4*)(OutF + row*LDO + col + 4);
        float* dst = of + ((size_t)(b*SQn + q0 + row))*DM + col;
        *(f32x4*)dst       = v0;
        *(f32x4*)(dst + 4) = v1;
    } else {
        u16* ob = (u16*)out;
        int row = t >> 5, col = (t & 31) * 8;
        f32x4 v0 = *(const f32x4*)(OutF + row*LDO + col);
        f32x4 v1 = *(const f32x4*)(OutF + row*LDO + col + 4);
        u32x4 pk;
        pk[0] = (u32)f2bf(v0[0]) | ((u32)f2bf(v0[1]) << 16);
        pk[1] = (u32)f2bf(v0[2]) | ((u32)f2bf(v0[3]) << 16);
        pk[2] = (u32)f2bf(v1[0]) | ((u32)f2bf(v1[1]) << 16);
        pk[3] = (u32)f2bf(v1[2]) | ((u32)f2bf(v1[3]) << 16);
        *(u32x4*)(ob + ((size_t)(b*SQn + q0 + row))*DM + col) = pk;
    }
}

// ---------------------------------------------------------------------------
extern "C" void kernel_launch(void* const* d_in, const int* in_sizes, int n_in,
                              void* d_out, int out_size, void* d_ws, size_t ws_size,
                              hipStream_t stream)
{
    const void* query  = d_in[0];
    const void* values = d_in[1];
    const void* dist   = d_in[2];
    const void* Wq     = d_in[3];
    const void* Wqb    = d_in[4];
    const void* Wk     = d_in[5];
    const void* Wkb    = d_in[6];
    const void* Wv     = d_in[7];
    const void* Wvb    = d_in[8];
    const void* fcw    = d_in[9];
    const void* fcb    = d_in[10];
    const void* tkeys  = d_in[11];

    char* ws   = (char*)d_ws;
    f16*  qf   = (f16*)ws;                     // 4 MB   [s][256] f16
    f16*  kf   = (f16*)(ws + (4u << 20));      // 1 MB   [h][s][32] f16
    u16*  vt   = (u16*)(ws + (5u << 20));      // 4 MB   [b][h][kt][...] bf16
    int*  flag = (int*)(ws + (9u << 20));      // 4 B
    float* dT  = (float*)(ws + (16u << 20));   // 64 MB  fragment-tiled dwv f32

    detect_kernel<<<1, 256, 0, stream>>>((const u32*)query, flag);
    proj_kernel<<<dim3(288, 4), 256, 0, stream>>>(flag, query, values, tkeys,
                                                  Wq, Wqb, Wk, Wkb, Wv, Wvb,
                                                  qf, kf, vt);
    dwsum_kernel<<<dim3(BB * SQn), 256, 0, stream>>>(flag, dist, dT);
    attn_kernel<<<dim3(64, 4), 1024, 0, stream>>>(flag, dT, qf, kf, vt, fcw, fcb, d_out);
}

// Round 8
// 193.993 us; speedup vs baseline: 1.2165x; 1.2165x over previous
//
#include <hip/hip_runtime.h>

#define BB 4
#define SQn 2048
#define SS 2048
#define DM 256
#define DH 32

typedef unsigned short u16;
typedef unsigned int u32;
typedef _Float16 f16;
typedef __attribute__((ext_vector_type(8))) f16 f16x8;
typedef __attribute__((ext_vector_type(4))) f16 f16x4;
typedef __attribute__((ext_vector_type(8))) short s16x8;
typedef __attribute__((ext_vector_type(4))) float f32x4;
typedef __attribute__((ext_vector_type(2))) float f32x2;
typedef __attribute__((ext_vector_type(4))) u32 u32x4;
typedef __attribute__((ext_vector_type(2))) u32 u32x2;

__device__ __forceinline__ float bf2f(u16 x){ u32 u=((u32)x)<<16; return __builtin_bit_cast(float,u); }
__device__ __forceinline__ u16 f2bf(float f){ u32 u=__builtin_bit_cast(u32,f); u32 r=(u+0x7fffu+((u>>16)&1u))>>16; return (u16)r; }

// Load 8 consecutive elements as f16 from bf16 (fl=0) or fp32 (fl=1) buffer.
__device__ __forceinline__ f16x8 ld8(const void* p, size_t off, int fl)
{
    f16x8 r;
    if (fl) {
        const float* f = (const float*)p + off;
        f32x4 a = *(const f32x4*)f;
        f32x4 b = *(const f32x4*)(f + 4);
        #pragma unroll
        for (int i = 0; i < 4; ++i) { r[i] = (f16)a[i]; r[4+i] = (f16)b[i]; }
    } else {
        const u16* s = (const u16*)p + off;
        u32x4 v = *(const u32x4*)s;
        #pragma unroll
        for (int i = 0; i < 4; ++i) {
            u32 x = v[i];
            r[2*i]   = (f16)bf2f((u16)(x & 0xffff));
            r[2*i+1] = (f16)bf2f((u16)(x >> 16));
        }
    }
    return r;
}
__device__ __forceinline__ float ld1(const void* p, int idx, int fl)
{ return fl ? ((const float*)p)[idx] : bf2f(((const u16*)p)[idx]); }

// ---------------------------------------------------------------------------
// Dtype detection: 0 = bf16 inputs, 1 = fp32 inputs.
// ---------------------------------------------------------------------------
__global__ void detect_kernel(const u32* __restrict__ q, int* __restrict__ flag)
{
    int t = threadIdx.x;                 // 256
    u32 w = q[t];
    u32 e = (w >> 7) & 0xFFu;
    int vote = ((e >= 0x70u && e <= 0x85u) || ((w & 0xFFFFu) == 0u)) ? 1 : 0;
    #pragma unroll
    for (int d = 1; d < 64; d <<= 1) vote += __shfl_xor(vote, d);
    __shared__ int ps[4];
    if ((t & 63) == 0) ps[t >> 6] = vote;
    __syncthreads();
    if (t == 0) *flag = ((ps[0]+ps[1]+ps[2]+ps[3]) >= 128) ? 0 : 1;
}

// ---------------------------------------------------------------------------
// Kernel A: fused projections (f16 MFMA).
//   q -> qf f16 [s][256]
//   k -> kf2 f16 [h][s][32]                   (per-head contiguous: coalesced bk)
//   v -> vt2 bf16 [b][h][kt][nt][quad][l15][8] (MFMA-fragment order: coalesced bv)
// ---------------------------------------------------------------------------
__global__ __launch_bounds__(256) void proj_kernel(
    const int* __restrict__ flag,
    const void* __restrict__ query, const void* __restrict__ values, const void* __restrict__ tkeys,
    const void* __restrict__ Wq, const void* __restrict__ Wqb,
    const void* __restrict__ Wk, const void* __restrict__ Wkb,
    const void* __restrict__ Wv, const void* __restrict__ Wvb,
    f16* __restrict__ qf, f16* __restrict__ kf, u16* __restrict__ vt)
{
    int fl = *flag;
    int bx = blockIdx.x;
    const void *X, *W, *Bi; int mode, rowbase;
    if (bx < 128)      { X=query;  W=Wq; Bi=Wqb; mode=0; rowbase=bx*64; }
    else if (bx < 256) { X=values; W=Wv; Bi=Wvb; mode=2; rowbase=(bx-128)*64; }
    else               { X=tkeys;  W=Wk; Bi=Wkb; mode=1; rowbase=(bx-256)*64; }
    int colbase = blockIdx.y * 64;

    __shared__ f16 Xs[64][40];
    __shared__ f16 Ws[64][40];
    __shared__ u16 Os[64][72];

    int t = threadIdx.x;
    int lane = t & 63, w = t >> 6;
    int quad = lane >> 4, l15 = lane & 15;

    const f32x4 fz = {0.f,0.f,0.f,0.f};
    f32x4 acc[4] = {fz,fz,fz,fz};

    for (int ks = 0; ks < 8; ++ks) {
        int k0 = ks * 32;
        {
            int row = t >> 2, ch = (t & 3) * 8;
            f16x8 xv = ld8(X, (size_t)(rowbase+row)*DM + k0 + ch, fl);
            f16x8 wv = ld8(W, (size_t)(colbase+row)*DM + k0 + ch, fl);
            *(f16x8*)(&Xs[row][ch]) = xv;
            *(f16x8*)(&Ws[row][ch]) = wv;
        }
        __syncthreads();
        f16x8 a = *(const f16x8*)(&Xs[w*16 + l15][quad*8]);
        #pragma unroll
        for (int nt = 0; nt < 4; ++nt) {
            f16x8 bfr = *(const f16x8*)(&Ws[nt*16 + l15][quad*8]);
            acc[nt] = __builtin_amdgcn_mfma_f32_16x16x32_f16(a, bfr, acc[nt], 0, 0, 0);
        }
        __syncthreads();
    }

    if (mode == 2) {
        // vt2 fragment-interleaved store
        int m = rowbase + w*16 + quad*4;     // 4 consecutive seq positions
        int bb = m >> 11, s = m & 2047;
        int ktv = s >> 5, qv = (s >> 3) & 3, kk = s & 7;   // kk in {0,4}
        #pragma unroll
        for (int nt = 0; nt < 4; ++nt) {
            int col = colbase + nt*16 + l15;
            float bv = ld1(Bi, col, fl);
            int hv = col >> 5, ntv = (col >> 4) & 1;
            size_t idx = (((((size_t)(bb*8 + hv))*64 + ktv)*2 + ntv)*4 + qv)*128
                         + (size_t)(col & 15)*8 + kk;
            u32x2 pk;
            pk[0] = (u32)f2bf(acc[nt][0]+bv) | ((u32)f2bf(acc[nt][1]+bv) << 16);
            pk[1] = (u32)f2bf(acc[nt][2]+bv) | ((u32)f2bf(acc[nt][3]+bv) << 16);
            *(u32x2*)(vt + idx) = pk;
        }
    } else {
        #pragma unroll
        for (int nt = 0; nt < 4; ++nt) {
            int col = nt*16 + l15;
            float bv = ld1(Bi, colbase + col, fl);
            #pragma unroll
            for (int r = 0; r < 4; ++r)
                Os[w*16 + quad*4 + r][col] = __builtin_bit_cast(u16, (f16)(acc[nt][r] + bv));
        }
        __syncthreads();
        #pragma unroll
        for (int p = 0; p < 2; ++p) {
            int rr = (t >> 3) + p*32;
            int ch = (t & 7) * 8;
            u32x4 v = *(const u32x4*)(&Os[rr][ch]);
            if (mode == 0) {
                *(u32x4*)(qf + (size_t)(rowbase+rr)*DM + colbase + ch) = v;
            } else {
                int head = (colbase + ch) >> 5;
                int dh = ch & 31;
                *(u32x4*)(kf + (size_t)head*(SS*DH) + (size_t)(rowbase+rr)*DH + dh) = v;
            }
        }
    }
}

// ---------------------------------------------------------------------------
// Kernel B: per row q: rs = (1/sqrt(32)) / sum_k 1/(d+eps), then write
// dwv = (f16)(rs * rcpf(d+eps)) into distT, row-major [32 q][32 k] tiles:
//   distT[((b*64+qt)*64+kt)*1024 + (q&31)*32 + (k&31)]   (f16)
// Thread t covers k=t*8..t*8+7 -> ONE 16B store; threads 0-3 fill a 64B line
// (zero write amplification, vs r7's 2x on the fragment-interleaved f32 table).
// ---------------------------------------------------------------------------
__global__ __launch_bounds__(256) void dwsum_kernel(
    const int* __restrict__ flag, const void* __restrict__ dist, u16* __restrict__ distT)
{
    int fl = *flag;
    int row = blockIdx.x;                // b*2048 + q
    int t = threadIdx.x;

    float d[8];
    if (fl) {
        const float* p = (const float*)dist + (size_t)row * SS + t*8;
        f32x4 a = *(const f32x4*)p;
        f32x4 b4 = *(const f32x4*)(p + 4);
        #pragma unroll
        for (int i = 0; i < 4; ++i) { d[i] = a[i]; d[4+i] = b4[i]; }
    } else {
        const u16* p = (const u16*)dist + (size_t)row * SS + t*8;
        u32x4 v = *(const u32x4*)p;
        #pragma unroll
        for (int i = 0; i < 4; ++i) {
            u32 x = v[i];
            d[2*i]   = bf2f((u16)(x & 0xffff));
            d[2*i+1] = bf2f((u16)(x >> 16));
        }
    }
    float s = 0.f;
    #pragma unroll
    for (int i = 0; i < 8; ++i) s += 1.0f / (d[i] + 1e-9f);
    #pragma unroll
    for (int dd = 1; dd < 64; dd <<= 1) s += __shfl_xor(s, dd);
    __shared__ float ps[4];
    __shared__ float srs;
    if ((t & 63) == 0) ps[t >> 6] = s;
    __syncthreads();
    if (t == 0) srs = 0.17677669529663687f / (ps[0] + ps[1] + ps[2] + ps[3]);
    __syncthreads();
    float rs = srs;

    int b = row >> 11, q = row & 2047;
    int qt = q >> 5, ql = q & 31;
    size_t base = ((size_t)((b*64 + qt)*64 + (t >> 2)))*1024 + ql*32 + (t & 3)*8;
    u32x4 pk;
    #pragma unroll
    for (int i = 0; i < 4; ++i) {
        u16 lo = __builtin_bit_cast(u16, (f16)(rs * __builtin_amdgcn_rcpf(d[2*i]   + 1e-9f)));
        u16 hi = __builtin_bit_cast(u16, (f16)(rs * __builtin_amdgcn_rcpf(d[2*i+1] + 1e-9f)));
        pk[i] = (u32)lo | ((u32)hi << 16);
    }
    *(u32x4*)(distT + base) = pk;
}

// ---------------------------------------------------------------------------
// Kernel C: flash attention (no-max softmax, S^T orientation) + fused fc.
// 1 block = (b, 32 q-rows), 16 waves = 8 heads x 2 k-halves.  dwv precomputed
// in f16 row-major tiles: staging is a linear 2KB copy per tile; LDS buffer is
// row-padded [32][36] f16 so the fragment read (72B row stride) is ~2-way
// (free).  Softmax in loop = exp(st * cvt(dwv)) only.
// ---------------------------------------------------------------------------
#define LDP 40
#define LDO 264
#define DB_OFF 53248
#define OL_OFF  49152
#define OUTF_OFF 66048

__global__ __launch_bounds__(1024) void attn_kernel(
    const int* __restrict__ flag,
    const u16* __restrict__ distT,
    const f16* __restrict__ qf, const f16* __restrict__ kf, const u16* __restrict__ vtg,
    const void* __restrict__ fcw, const void* __restrict__ fcb,
    void* __restrict__ out)
{
    __shared__ __align__(16) char smem[99840];
    // loop:   P slices [16][32][LDP] u16 at 0 (40960);
    //         dwv dbuf 4x[32][36] f16 at 53248 (9216): buf (phase*2+group)
    // combine: Cx f32 [512][24] at 0 (49152)  (dwv bufs dead by then; disjoint anyway)
    // epilog:  Ol f16 [32][LDO] at 49152 (16896, dwv dead); OutF f32 [32][LDO] at 66048

    int fl = *flag;
    int t = threadIdx.x;
    int w = t >> 6, lane = t & 63;
    int quad = lane >> 4, l15 = lane & 15;
    int b = blockIdx.y, q0 = blockIdx.x * 32;
    int h = w & 7, khalf = w >> 3;

    u16* Pw = (u16*)(smem + w * 2560);
    u16* dbU = (u16*)(smem + DB_OFF);

    f16x8 aq[2];
    #pragma unroll
    for (int mt = 0; mt < 2; ++mt)
        aq[mt] = *(const f16x8*)(qf + (size_t)(b*SQn + q0 + mt*16 + l15)*DM + h*DH + quad*8);

    // ones-column B-fragment (bf16): B[k][0]=1, else 0 -> row-sum via MFMA
    u32 ov = (l15 == 0) ? 0x3F803F80u : 0u;
    u32x4 ovv = {ov, ov, ov, ov};
    s16x8 ones = __builtin_bit_cast(s16x8, ovv);

    const f32x4 fz = {0.f,0.f,0.f,0.f};
    f32x4 o[2][2] = {{fz,fz},{fz,fz}};
    f32x4 lacc[2] = {fz, fz};

    const f16* kfh = kf + (size_t)h * (SS*DH);
    const u16* vth = vtg + (((size_t)(b*8 + h)) << 16);   // * 64 kt * 1024 u16
    const u16* dTb = distT + ((size_t)(b*64 + blockIdx.x))*64*1024;

    // dwv staging: thread group g (== its waves' khalf) stages that group's tile
    int g  = t >> 9;
    int tt = t & 511;
    int drow = tt >> 4, dcol = (tt & 15)*2;   // elem (drow, dcol..dcol+1) of [32][32]

    // ---- prologue: stage dwv tile 0 (both groups); load K/V tile 0 ----
    {
        u32 sv = *(const u32*)(dTb + (size_t)(g*32)*1024 + tt*2);
        *(u32*)(dbU + g*1152 + drow*36 + dcol) = sv;
    }
    f16x8 ck[2]; s16x8 cv[2];
    {
        int ktg0 = khalf * 32;
        #pragma unroll
        for (int nt = 0; nt < 2; ++nt) {
            ck[nt] = *(const f16x8*)(kfh + (size_t)(ktg0*32 + nt*16 + l15)*DH + quad*8);
            cv[nt] = __builtin_bit_cast(s16x8,
                *(const u32x4*)(vth + (size_t)ktg0*1024 + nt*512 + quad*128 + l15*8));
        }
    }
    __syncthreads();

    for (int kt = 0; kt < 32; ++kt) {
        int ktn  = (kt + 1) & 31;                // wrap: last prefetch reads valid memory
        int ktgn = khalf*32 + ktn;

        // issue next-tile loads early (hide under compute; barrier drains them)
        u32 sv = *(const u32*)(dTb + (size_t)(g*32 + ktn)*1024 + tt*2);
        f16x8 nk[2]; s16x8 nv[2];
        #pragma unroll
        for (int nt = 0; nt < 2; ++nt) {
            nk[nt] = *(const f16x8*)(kfh + (size_t)(ktgn*32 + nt*16 + l15)*DH + quad*8);
            nv[nt] = __builtin_bit_cast(s16x8,
                *(const u32x4*)(vth + (size_t)ktgn*1024 + nt*512 + quad*128 + l15*8));
        }

        // dwv fragment from LDS (padded rows: ~2-way banked = free)
        const u16* dbc = dbU + ((kt & 1)*2 + khalf)*1152;
        f16x4 ddh[2][2];
        #pragma unroll
        for (int mt = 0; mt < 2; ++mt)
            #pragma unroll
            for (int nt = 0; nt < 2; ++nt)
                ddh[mt][nt] = *(const f16x4*)(dbc + (mt*16 + l15)*36 + nt*16 + quad*4);

        // S^T = K·Q^T : C elem (key = nt*16+quad*4+r, q = mt*16+l15)
        f32x4 st[2][2];
        #pragma unroll
        for (int mt = 0; mt < 2; ++mt)
            #pragma unroll
            for (int nt = 0; nt < 2; ++nt)
                st[mt][nt] = __builtin_amdgcn_mfma_f32_16x16x32_f16(ck[nt], aq[mt], fz, 0, 0, 0);

        // softmax-lite: p = exp(st * dwv)  (dwv precomputed; no rcp/add here)
        #pragma unroll
        for (int mt = 0; mt < 2; ++mt)
            #pragma unroll
            for (int nt = 0; nt < 2; ++nt) {
                u32 pb[4];
                #pragma unroll
                for (int r = 0; r < 4; ++r) {
                    float p = __expf(st[mt][nt][r] * (float)ddh[mt][nt][r]);
                    pb[r] = __builtin_bit_cast(u32, p);
                }
                u32x2 pk;
                pk[0] = __builtin_amdgcn_perm(pb[1], pb[0], 0x07060302u);  // [p1.hi16|p0.hi16]
                pk[1] = __builtin_amdgcn_perm(pb[3], pb[2], 0x07060302u);
                *(u32x2*)(Pw + (mt*16 + l15)*LDP + nt*16 + quad*4) = pk;
            }
        __asm__ __volatile__("" ::: "memory");   // order the per-wave LDS transpose

        // P @ [V | 1] in bf16 (l arrives in o's C-layout; same rounded p in num & denom)
        #pragma unroll
        for (int mt = 0; mt < 2; ++mt) {
            s16x8 ap = *(const s16x8*)(Pw + (mt*16 + l15)*LDP + quad*8);
            lacc[mt] = __builtin_amdgcn_mfma_f32_16x16x32_bf16(ap, ones, lacc[mt], 0, 0, 0);
            #pragma unroll
            for (int nt = 0; nt < 2; ++nt)
                o[mt][nt] = __builtin_amdgcn_mfma_f32_16x16x32_bf16(ap, cv[nt], o[mt][nt], 0, 0, 0);
        }

        // write next dwv tile into the other phase buffer; barrier publishes it
        *(u32*)(dbU + (((kt + 1) & 1)*2 + g)*1152 + drow*36 + dcol) = sv;
        __syncthreads();

        ck[0] = nk[0]; ck[1] = nk[1]; cv[0] = nv[0]; cv[1] = nv[1];
    }

    // ---- combine the two k-halves (plain sums: no-max softmax is linear in k) ----
    float* Cx = (float*)smem;              // [512][24] f32
    if (w >= 8) {
        float* dst = Cx + ((w - 8)*64 + lane)*24;
        *(f32x4*)(dst +  0) = o[0][0];
        *(f32x4*)(dst +  4) = o[0][1];
        *(f32x4*)(dst +  8) = o[1][0];
        *(f32x4*)(dst + 12) = o[1][1];
        *(f32x4*)(dst + 16) = lacc[0];
        *(f32x4*)(dst + 20) = lacc[1];
    }
    __syncthreads();
    f16* Ol = (f16*)(smem + OL_OFF);       // [32][LDO]
    if (w < 8) {
        const float* src = Cx + (w*64 + lane)*24;
        o[0][0] += *(const f32x4*)(src +  0);
        o[0][1] += *(const f32x4*)(src +  4);
        o[1][0] += *(const f32x4*)(src +  8);
        o[1][1] += *(const f32x4*)(src + 12);
        lacc[0] += *(const f32x4*)(src + 16);
        lacc[1] += *(const f32x4*)(src + 20);

        // normalize: l for row (mt,quad,r) lives at lane (l15=0, quad), col 0
        #pragma unroll
        for (int mt = 0; mt < 2; ++mt)
            #pragma unroll
            for (int r = 0; r < 4; ++r) {
                float lv = __shfl(lacc[mt][r], lane & 48);
                float inv = 1.0f / lv;
                o[mt][0][r] *= inv;
                o[mt][1][r] *= inv;
            }

        #pragma unroll
        for (int mt = 0; mt < 2; ++mt)
            #pragma unroll
            for (int nt = 0; nt < 2; ++nt)
                #pragma unroll
                for (int r = 0; r < 4; ++r)
                    Ol[(mt*16 + quad*4 + r)*LDO + h*DH + nt*16 + l15] = (f16)o[mt][nt][r];
    }
    __syncthreads();

    // ---- fused fc across all 16 waves: wave w owns output cols w*16..w*16+15 ----
    f32x4 c[2] = {fz, fz};
    int n = w*16 + l15;
    for (int ks = 0; ks < 8; ++ks) {
        f16x8 bw = ld8(fcw, (size_t)n*DM + ks*32 + quad*8, fl);
        #pragma unroll
        for (int mt = 0; mt < 2; ++mt) {
            f16x8 a2 = *(const f16x8*)(Ol + (mt*16 + l15)*LDO + ks*32 + quad*8);
            c[mt] = __builtin_amdgcn_mfma_f32_16x16x32_f16(a2, bw, c[mt], 0, 0, 0);
        }
    }
    float* OutF = (float*)(smem + OUTF_OFF);  // [32][LDO] f32
    {
        float bv = ld1(fcb, n, fl);
        #pragma unroll
        for (int mt = 0; mt < 2; ++mt)
            #pragma unroll
            for (int r = 0; r < 4; ++r)
                OutF[(mt*16 + quad*4 + r)*LDO + n] = c[mt][r] + bv;
    }
    __syncthreads();
    if (fl) {
        float* of = (float*)out;
        int row = t >> 5, col = (t & 31) * 8;
        f32x4 v0 = *(const f32x4*)(OutF + row*LDO + col);
        f32x4 v1 = *(const f32x4*)(OutF + row*LDO + col + 4);
        float* dst = of + ((size_t)(b*SQn + q0 + row))*DM + col;
        *(f32x4*)dst       = v0;
        *(f32x4*)(dst + 4) = v1;
    } else {
        u16* ob = (u16*)out;
        int row = t >> 5, col = (t & 31) * 8;
        f32x4 v0 = *(const f32x4*)(OutF + row*LDO + col);
        f32x4 v1 = *(const f32x4*)(OutF + row*LDO + col + 4);
        u32x4 pk;
        pk[0] = (u32)f2bf(v0[0]) | ((u32)f2bf(v0[1]) << 16);
        pk[1] = (u32)f2bf(v0[2]) | ((u32)f2bf(v0[3]) << 16);
        pk[2] = (u32)f2bf(v1[0]) | ((u32)f2bf(v1[1]) << 16);
        pk[3] = (u32)f2bf(v1[2]) | ((u32)f2bf(v1[3]) << 16);
        *(u32x4*)(ob + ((size_t)(b*SQn + q0 + row))*DM + col) = pk;
    }
}

// ---------------------------------------------------------------------------
extern "C" void kernel_launch(void* const* d_in, const int* in_sizes, int n_in,
                              void* d_out, int out_size, void* d_ws, size_t ws_size,
                              hipStream_t stream)
{
    const void* query  = d_in[0];
    const void* values = d_in[1];
    const void* dist   = d_in[2];
    const void* Wq     = d_in[3];
    const void* Wqb    = d_in[4];
    const void* Wk     = d_in[5];
    const void* Wkb    = d_in[6];
    const void* Wv     = d_in[7];
    const void* Wvb    = d_in[8];
    const void* fcw    = d_in[9];
    const void* fcb    = d_in[10];
    const void* tkeys  = d_in[11];

    char* ws   = (char*)d_ws;
    f16*  qf   = (f16*)ws;                     // 4 MB   [s][256] f16
    f16*  kf   = (f16*)(ws + (4u << 20));      // 1 MB   [h][s][32] f16
    u16*  vt   = (u16*)(ws + (5u << 20));      // 4 MB   [b][h][kt][...] bf16
    int*  flag = (int*)(ws + (9u << 20));      // 4 B
    u16*  dT   = (u16*)(ws + (16u << 20));     // 32 MB  row-major-tiled dwv f16

    detect_kernel<<<1, 256, 0, stream>>>((const u32*)query, flag);
    proj_kernel<<<dim3(288, 4), 256, 0, stream>>>(flag, query, values, tkeys,
                                                  Wq, Wqb, Wk, Wkb, Wv, Wvb,
                                                  qf, kf, vt);
    dwsum_kernel<<<dim3(BB * SQn), 256, 0, stream>>>(flag, dist, dT);
    attn_kernel<<<dim3(64, 4), 1024, 0, stream>>>(flag, dT, qf, kf, vt, fcw, fcb, d_out);
}

// Round 9
// 191.702 us; speedup vs baseline: 1.2311x; 1.0120x over previous
//
#include <hip/hip_runtime.h>

#define BB 4
#define SQn 2048
#define SS 2048
#define DM 256
#define DH 32

typedef unsigned short u16;
typedef unsigned int u32;
typedef _Float16 f16;
typedef __attribute__((ext_vector_type(8))) f16 f16x8;
typedef __attribute__((ext_vector_type(4))) f16 f16x4;
typedef __attribute__((ext_vector_type(8))) short s16x8;
typedef __attribute__((ext_vector_type(4))) float f32x4;
typedef __attribute__((ext_vector_type(2))) float f32x2;
typedef __attribute__((ext_vector_type(4))) u32 u32x4;
typedef __attribute__((ext_vector_type(2))) u32 u32x2;

__device__ __forceinline__ float bf2f(u16 x){ u32 u=((u32)x)<<16; return __builtin_bit_cast(float,u); }
__device__ __forceinline__ u16 f2bf(float f){ u32 u=__builtin_bit_cast(u32,f); u32 r=(u+0x7fffu+((u>>16)&1u))>>16; return (u16)r; }

// Wave-level dtype self-detection (replaces detect_kernel; saves a launch).
// bf16 input: word = 2x bf16, (w>>7)&0xFF is bf16#0's exponent field -> in
// [0x70,0x85] for ~97% of N(0,1) samples.  f32 input: those bits are mantissa
// -> ~8.6% hit rate.  64-sample vote at threshold 32: error prob negligible.
__device__ __forceinline__ int detect_fl(const u32* __restrict__ q)
{
    u32 w = q[threadIdx.x & 63];
    u32 e = (w >> 7) & 0xFFu;
    int v = ((e >= 0x70u && e <= 0x85u) || ((w & 0xFFFFu) == 0u)) ? 1 : 0;
    unsigned long long b = __ballot(v);
    return (__popcll(b) >= 32) ? 0 : 1;
}

// Load 8 consecutive elements as f16 from bf16 (fl=0) or fp32 (fl=1) buffer.
__device__ __forceinline__ f16x8 ld8(const void* p, size_t off, int fl)
{
    f16x8 r;
    if (fl) {
        const float* f = (const float*)p + off;
        f32x4 a = *(const f32x4*)f;
        f32x4 b = *(const f32x4*)(f + 4);
        #pragma unroll
        for (int i = 0; i < 4; ++i) { r[i] = (f16)a[i]; r[4+i] = (f16)b[i]; }
    } else {
        const u16* s = (const u16*)p + off;
        u32x4 v = *(const u32x4*)s;
        #pragma unroll
        for (int i = 0; i < 4; ++i) {
            u32 x = v[i];
            r[2*i]   = (f16)bf2f((u16)(x & 0xffff));
            r[2*i+1] = (f16)bf2f((u16)(x >> 16));
        }
    }
    return r;
}
__device__ __forceinline__ float ld1(const void* p, int idx, int fl)
{ return fl ? ((const float*)p)[idx] : bf2f(((const u16*)p)[idx]); }

// ---------------------------------------------------------------------------
// Mega kernel: proj (blocks 0..1151) + dwsum (blocks 1152..9343), bodies
// verbatim from r8.  Independent work fused to remove a launch boundary and
// let dwsum's BW phase backfill proj's latency phases.
//   proj: q -> qf f16 [s][256]; k -> kf2 f16 [h][s][32];
//         v -> vt2 bf16 [b][h][kt][nt][quad][l15][8]
//   dwsum: distT f16 row-major [32 q][32 k] tiles of dwv = rs*rcp(d+eps)
// ---------------------------------------------------------------------------
__global__ __launch_bounds__(256) void mega_kernel(
    const void* __restrict__ query, const void* __restrict__ values, const void* __restrict__ tkeys,
    const void* __restrict__ Wq, const void* __restrict__ Wqb,
    const void* __restrict__ Wk, const void* __restrict__ Wkb,
    const void* __restrict__ Wv, const void* __restrict__ Wvb,
    const void* __restrict__ dist,
    f16* __restrict__ qf, f16* __restrict__ kf, u16* __restrict__ vt,
    u16* __restrict__ distT)
{
    __shared__ __align__(16) char sm[19968];
    int fl = detect_fl((const u32*)query);
    int x = blockIdx.x;
    int t = threadIdx.x;

    if (x < 1152) {
        // ================= proj =================
        int pbx = x >> 2, pby = x & 3;
        const void *X, *W, *Bi; int mode, rowbase;
        if (pbx < 128)      { X=query;  W=Wq; Bi=Wqb; mode=0; rowbase=pbx*64; }
        else if (pbx < 256) { X=values; W=Wv; Bi=Wvb; mode=2; rowbase=(pbx-128)*64; }
        else                { X=tkeys;  W=Wk; Bi=Wkb; mode=1; rowbase=(pbx-256)*64; }
        int colbase = pby * 64;

        f16 (*Xs)[40] = (f16(*)[40])sm;             //  5120 B
        f16 (*Ws)[40] = (f16(*)[40])(sm + 5120);    //  5120 B
        u16 (*Os)[72] = (u16(*)[72])(sm + 10240);   //  9216 B

        int lane = t & 63, w = t >> 6;
        int quad = lane >> 4, l15 = lane & 15;

        const f32x4 fz = {0.f,0.f,0.f,0.f};
        f32x4 acc[4] = {fz,fz,fz,fz};

        for (int ks = 0; ks < 8; ++ks) {
            int k0 = ks * 32;
            {
                int row = t >> 2, ch = (t & 3) * 8;
                f16x8 xv = ld8(X, (size_t)(rowbase+row)*DM + k0 + ch, fl);
                f16x8 wv = ld8(W, (size_t)(colbase+row)*DM + k0 + ch, fl);
                *(f16x8*)(&Xs[row][ch]) = xv;
                *(f16x8*)(&Ws[row][ch]) = wv;
            }
            __syncthreads();
            f16x8 a = *(const f16x8*)(&Xs[w*16 + l15][quad*8]);
            #pragma unroll
            for (int nt = 0; nt < 4; ++nt) {
                f16x8 bfr = *(const f16x8*)(&Ws[nt*16 + l15][quad*8]);
                acc[nt] = __builtin_amdgcn_mfma_f32_16x16x32_f16(a, bfr, acc[nt], 0, 0, 0);
            }
            __syncthreads();
        }

        if (mode == 2) {
            int m = rowbase + w*16 + quad*4;
            int bb = m >> 11, s = m & 2047;
            int ktv = s >> 5, qv = (s >> 3) & 3, kk = s & 7;
            #pragma unroll
            for (int nt = 0; nt < 4; ++nt) {
                int col = colbase + nt*16 + l15;
                float bv = ld1(Bi, col, fl);
                int hv = col >> 5, ntv = (col >> 4) & 1;
                size_t idx = (((((size_t)(bb*8 + hv))*64 + ktv)*2 + ntv)*4 + qv)*128
                             + (size_t)(col & 15)*8 + kk;
                u32x2 pk;
                pk[0] = (u32)f2bf(acc[nt][0]+bv) | ((u32)f2bf(acc[nt][1]+bv) << 16);
                pk[1] = (u32)f2bf(acc[nt][2]+bv) | ((u32)f2bf(acc[nt][3]+bv) << 16);
                *(u32x2*)(vt + idx) = pk;
            }
        } else {
            #pragma unroll
            for (int nt = 0; nt < 4; ++nt) {
                int col = nt*16 + l15;
                float bv = ld1(Bi, colbase + col, fl);
                #pragma unroll
                for (int r = 0; r < 4; ++r)
                    Os[w*16 + quad*4 + r][col] = __builtin_bit_cast(u16, (f16)(acc[nt][r] + bv));
            }
            __syncthreads();
            #pragma unroll
            for (int p = 0; p < 2; ++p) {
                int rr = (t >> 3) + p*32;
                int ch = (t & 7) * 8;
                u32x4 v = *(const u32x4*)(&Os[rr][ch]);
                if (mode == 0) {
                    *(u32x4*)(qf + (size_t)(rowbase+rr)*DM + colbase + ch) = v;
                } else {
                    int head = (colbase + ch) >> 5;
                    int dh = ch & 31;
                    *(u32x4*)(kf + (size_t)head*(SS*DH) + (size_t)(rowbase+rr)*DH + dh) = v;
                }
            }
        }
    } else {
        // ================= dwsum =================
        int row = x - 1152;                  // b*2048 + q
        float* ps  = (float*)sm;
        float* srs = (float*)(sm + 16);

        float d[8];
        if (fl) {
            const float* p = (const float*)dist + (size_t)row * SS + t*8;
            f32x4 a = *(const f32x4*)p;
            f32x4 b4 = *(const f32x4*)(p + 4);
            #pragma unroll
            for (int i = 0; i < 4; ++i) { d[i] = a[i]; d[4+i] = b4[i]; }
        } else {
            const u16* p = (const u16*)dist + (size_t)row * SS + t*8;
            u32x4 v = *(const u32x4*)p;
            #pragma unroll
            for (int i = 0; i < 4; ++i) {
                u32 xw = v[i];
                d[2*i]   = bf2f((u16)(xw & 0xffff));
                d[2*i+1] = bf2f((u16)(xw >> 16));
            }
        }
        float s = 0.f;
        #pragma unroll
        for (int i = 0; i < 8; ++i) s += 1.0f / (d[i] + 1e-9f);
        #pragma unroll
        for (int dd = 1; dd < 64; dd <<= 1) s += __shfl_xor(s, dd);
        if ((t & 63) == 0) ps[t >> 6] = s;
        __syncthreads();
        if (t == 0) *srs = 0.17677669529663687f / (ps[0] + ps[1] + ps[2] + ps[3]);
        __syncthreads();
        float rs = *srs;

        int b = row >> 11, q = row & 2047;
        int qt = q >> 5, ql = q & 31;
        size_t base = ((size_t)((b*64 + qt)*64 + (t >> 2)))*1024 + ql*32 + (t & 3)*8;
        u32x4 pk;
        #pragma unroll
        for (int i = 0; i < 4; ++i) {
            u16 lo = __builtin_bit_cast(u16, (f16)(rs * __builtin_amdgcn_rcpf(d[2*i]   + 1e-9f)));
            u16 hi = __builtin_bit_cast(u16, (f16)(rs * __builtin_amdgcn_rcpf(d[2*i+1] + 1e-9f)));
            pk[i] = (u32)lo | ((u32)hi << 16);
        }
        *(u32x4*)(distT + base) = pk;
    }
}

// ---------------------------------------------------------------------------
// Kernel C: flash attention (no-max softmax, S^T orientation) + fused fc.
// 1 block = (b, 32 q-rows), 16 waves = 8 heads x 2 k-halves.  Unchanged from
// r8 except self-detect (control kernel for this round's launch-fusion probe).
// ---------------------------------------------------------------------------
#define LDP 40
#define LDO 264
#define DB_OFF 53248
#define OL_OFF  49152
#define OUTF_OFF 66048

__global__ __launch_bounds__(1024) void attn_kernel(
    const void* __restrict__ queryp,
    const u16* __restrict__ distT,
    const f16* __restrict__ qf, const f16* __restrict__ kf, const u16* __restrict__ vtg,
    const void* __restrict__ fcw, const void* __restrict__ fcb,
    void* __restrict__ out)
{
    __shared__ __align__(16) char smem[99840];
    // loop:   P slices [16][32][LDP] u16 at 0 (40960);
    //         dwv dbuf 4x[32][36] f16 at 53248 (9216): buf (phase*2+group)
    // combine: Cx f32 [512][24] at 0 (49152)
    // epilog:  Ol f16 [32][LDO] at 49152 (16896); OutF f32 [32][LDO] at 66048

    int fl = detect_fl((const u32*)queryp);
    int t = threadIdx.x;
    int w = t >> 6, lane = t & 63;
    int quad = lane >> 4, l15 = lane & 15;
    int b = blockIdx.y, q0 = blockIdx.x * 32;
    int h = w & 7, khalf = w >> 3;

    u16* Pw = (u16*)(smem + w * 2560);
    u16* dbU = (u16*)(smem + DB_OFF);

    f16x8 aq[2];
    #pragma unroll
    for (int mt = 0; mt < 2; ++mt)
        aq[mt] = *(const f16x8*)(qf + (size_t)(b*SQn + q0 + mt*16 + l15)*DM + h*DH + quad*8);

    // ones-column B-fragment (bf16): B[k][0]=1, else 0 -> row-sum via MFMA
    u32 ov = (l15 == 0) ? 0x3F803F80u : 0u;
    u32x4 ovv = {ov, ov, ov, ov};
    s16x8 ones = __builtin_bit_cast(s16x8, ovv);

    const f32x4 fz = {0.f,0.f,0.f,0.f};
    f32x4 o[2][2] = {{fz,fz},{fz,fz}};
    f32x4 lacc[2] = {fz, fz};

    const f16* kfh = kf + (size_t)h * (SS*DH);
    const u16* vth = vtg + (((size_t)(b*8 + h)) << 16);   // * 64 kt * 1024 u16
    const u16* dTb = distT + ((size_t)(b*64 + blockIdx.x))*64*1024;

    // dwv staging: thread group g (== its waves' khalf) stages that group's tile
    int g  = t >> 9;
    int tt = t & 511;
    int drow = tt >> 4, dcol = (tt & 15)*2;   // elem (drow, dcol..dcol+1) of [32][32]

    // ---- prologue: stage dwv tile 0 (both groups); load K/V tile 0 ----
    {
        u32 sv = *(const u32*)(dTb + (size_t)(g*32)*1024 + tt*2);
        *(u32*)(dbU + g*1152 + drow*36 + dcol) = sv;
    }
    f16x8 ck[2]; s16x8 cv[2];
    {
        int ktg0 = khalf * 32;
        #pragma unroll
        for (int nt = 0; nt < 2; ++nt) {
            ck[nt] = *(const f16x8*)(kfh + (size_t)(ktg0*32 + nt*16 + l15)*DH + quad*8);
            cv[nt] = __builtin_bit_cast(s16x8,
                *(const u32x4*)(vth + (size_t)ktg0*1024 + nt*512 + quad*128 + l15*8));
        }
    }
    __syncthreads();

    for (int kt = 0; kt < 32; ++kt) {
        int ktn  = (kt + 1) & 31;                // wrap: last prefetch reads valid memory
        int ktgn = khalf*32 + ktn;

        // issue next-tile loads early (hide under compute; barrier drains them)
        u32 sv = *(const u32*)(dTb + (size_t)(g*32 + ktn)*1024 + tt*2);
        f16x8 nk[2]; s16x8 nv[2];
        #pragma unroll
        for (int nt = 0; nt < 2; ++nt) {
            nk[nt] = *(const f16x8*)(kfh + (size_t)(ktgn*32 + nt*16 + l15)*DH + quad*8);
            nv[nt] = __builtin_bit_cast(s16x8,
                *(const u32x4*)(vth + (size_t)ktgn*1024 + nt*512 + quad*128 + l15*8));
        }

        // dwv fragment from LDS (padded rows: ~2-way banked = free)
        const u16* dbc = dbU + ((kt & 1)*2 + khalf)*1152;
        f16x4 ddh[2][2];
        #pragma unroll
        for (int mt = 0; mt < 2; ++mt)
            #pragma unroll
            for (int nt = 0; nt < 2; ++nt)
                ddh[mt][nt] = *(const f16x4*)(dbc + (mt*16 + l15)*36 + nt*16 + quad*4);

        // S^T = K·Q^T : C elem (key = nt*16+quad*4+r, q = mt*16+l15)
        f32x4 st[2][2];
        #pragma unroll
        for (int mt = 0; mt < 2; ++mt)
            #pragma unroll
            for (int nt = 0; nt < 2; ++nt)
                st[mt][nt] = __builtin_amdgcn_mfma_f32_16x16x32_f16(ck[nt], aq[mt], fz, 0, 0, 0);

        // softmax-lite: p = exp(st * dwv)  (dwv precomputed; no rcp/add here)
        #pragma unroll
        for (int mt = 0; mt < 2; ++mt)
            #pragma unroll
            for (int nt = 0; nt < 2; ++nt) {
                u32 pb[4];
                #pragma unroll
                for (int r = 0; r < 4; ++r) {
                    float p = __expf(st[mt][nt][r] * (float)ddh[mt][nt][r]);
                    pb[r] = __builtin_bit_cast(u32, p);
                }
                u32x2 pk;
                pk[0] = __builtin_amdgcn_perm(pb[1], pb[0], 0x07060302u);  // [p1.hi16|p0.hi16]
                pk[1] = __builtin_amdgcn_perm(pb[3], pb[2], 0x07060302u);
                *(u32x2*)(Pw + (mt*16 + l15)*LDP + nt*16 + quad*4) = pk;
            }
        __asm__ __volatile__("" ::: "memory");   // order the per-wave LDS transpose

        // P @ [V | 1] in bf16 (l arrives in o's C-layout; same rounded p in num & denom)
        #pragma unroll
        for (int mt = 0; mt < 2; ++mt) {
            s16x8 ap = *(const s16x8*)(Pw + (mt*16 + l15)*LDP + quad*8);
            lacc[mt] = __builtin_amdgcn_mfma_f32_16x16x32_bf16(ap, ones, lacc[mt], 0, 0, 0);
            #pragma unroll
            for (int nt = 0; nt < 2; ++nt)
                o[mt][nt] = __builtin_amdgcn_mfma_f32_16x16x32_bf16(ap, cv[nt], o[mt][nt], 0, 0, 0);
        }

        // write next dwv tile into the other phase buffer; barrier publishes it
        *(u32*)(dbU + (((kt + 1) & 1)*2 + g)*1152 + drow*36 + dcol) = sv;
        __syncthreads();

        ck[0] = nk[0]; ck[1] = nk[1]; cv[0] = nv[0]; cv[1] = nv[1];
    }

    // ---- combine the two k-halves (plain sums: no-max softmax is linear in k) ----
    float* Cx = (float*)smem;              // [512][24] f32
    if (w >= 8) {
        float* dst = Cx + ((w - 8)*64 + lane)*24;
        *(f32x4*)(dst +  0) = o[0][0];
        *(f32x4*)(dst +  4) = o[0][1];
        *(f32x4*)(dst +  8) = o[1][0];
        *(f32x4*)(dst + 12) = o[1][1];
        *(f32x4*)(dst + 16) = lacc[0];
        *(f32x4*)(dst + 20) = lacc[1];
    }
    __syncthreads();
    f16* Ol = (f16*)(smem + OL_OFF);       // [32][LDO]
    if (w < 8) {
        const float* src = Cx + (w*64 + lane)*24;
        o[0][0] += *(const f32x4*)(src +  0);
        o[0][1] += *(const f32x4*)(src +  4);
        o[1][0] += *(const f32x4*)(src +  8);
        o[1][1] += *(const f32x4*)(src + 12);
        lacc[0] += *(const f32x4*)(src + 16);
        lacc[1] += *(const f32x4*)(src + 20);

        // normalize: l for row (mt,quad,r) lives at lane (l15=0, quad), col 0
        #pragma unroll
        for (int mt = 0; mt < 2; ++mt)
            #pragma unroll
            for (int r = 0; r < 4; ++r) {
                float lv = __shfl(lacc[mt][r], lane & 48);
                float inv = 1.0f / lv;
                o[mt][0][r] *= inv;
                o[mt][1][r] *= inv;
            }

        #pragma unroll
        for (int mt = 0; mt < 2; ++mt)
            #pragma unroll
            for (int nt = 0; nt < 2; ++nt)
                #pragma unroll
                for (int r = 0; r < 4; ++r)
                    Ol[(mt*16 + quad*4 + r)*LDO + h*DH + nt*16 + l15] = (f16)o[mt][nt][r];
    }
    __syncthreads();

    // ---- fused fc across all 16 waves: wave w owns output cols w*16..w*16+15 ----
    f32x4 c[2] = {fz, fz};
    int n = w*16 + l15;
    for (int ks = 0; ks < 8; ++ks) {
        f16x8 bw = ld8(fcw, (size_t)n*DM + ks*32 + quad*8, fl);
        #pragma unroll
        for (int mt = 0; mt < 2; ++mt) {
            f16x8 a2 = *(const f16x8*)(Ol + (mt*16 + l15)*LDO + ks*32 + quad*8);
            c[mt] = __builtin_amdgcn_mfma_f32_16x16x32_f16(a2, bw, c[mt], 0, 0, 0);
        }
    }
    float* OutF = (float*)(smem + OUTF_OFF);  // [32][LDO] f32
    {
        float bv = ld1(fcb, n, fl);
        #pragma unroll
        for (int mt = 0; mt < 2; ++mt)
            #pragma unroll
            for (int r = 0; r < 4; ++r)
                OutF[(mt*16 + quad*4 + r)*LDO + n] = c[mt][r] + bv;
    }
    __syncthreads();
    if (fl) {
        float* of = (float*)out;
        int row = t >> 5, col = (t & 31) * 8;
        f32x4 v0 = *(const f32x4*)(OutF + row*LDO + col);
        f32x4 v1 = *(const f32x4*)(OutF + row*LDO + col + 4);
        float* dst = of + ((size_t)(b*SQn + q0 + row))*DM + col;
        *(f32x4*)dst       = v0;
        *(f32x4*)(dst + 4) = v1;
    } else {
        u16* ob = (u16*)out;
        int row = t >> 5, col = (t & 31) * 8;
        f32x4 v0 = *(const f32x4*)(OutF + row*LDO + col);
        f32x4 v1 = *(const f32x4*)(OutF + row*LDO + col + 4);
        u32x4 pk;
        pk[0] = (u32)f2bf(v0[0]) | ((u32)f2bf(v0[1]) << 16);
        pk[1] = (u32)f2bf(v0[2]) | ((u32)f2bf(v0[3]) << 16);
        pk[2] = (u32)f2bf(v1[0]) | ((u32)f2bf(v1[1]) << 16);
        pk[3] = (u32)f2bf(v1[2]) | ((u32)f2bf(v1[3]) << 16);
        *(u32x4*)(ob + ((size_t)(b*SQn + q0 + row))*DM + col) = pk;
    }
}

// ---------------------------------------------------------------------------
extern "C" void kernel_launch(void* const* d_in, const int* in_sizes, int n_in,
                              void* d_out, int out_size, void* d_ws, size_t ws_size,
                              hipStream_t stream)
{
    const void* query  = d_in[0];
    const void* values = d_in[1];
    const void* dist   = d_in[2];
    const void* Wq     = d_in[3];
    const void* Wqb    = d_in[4];
    const void* Wk     = d_in[5];
    const void* Wkb    = d_in[6];
    const void* Wv     = d_in[7];
    const void* Wvb    = d_in[8];
    const void* fcw    = d_in[9];
    const void* fcb    = d_in[10];
    const void* tkeys  = d_in[11];

    char* ws   = (char*)d_ws;
    f16*  qf   = (f16*)ws;                     // 4 MB   [s][256] f16
    f16*  kf   = (f16*)(ws + (4u << 20));      // 1 MB   [h][s][32] f16
    u16*  vt   = (u16*)(ws + (5u << 20));      // 4 MB   [b][h][kt][...] bf16
    u16*  dT   = (u16*)(ws + (16u << 20));     // 32 MB  row-major-tiled dwv f16

    mega_kernel<<<dim3(1152 + BB*SQn), 256, 0, stream>>>(
        query, values, tkeys, Wq, Wqb, Wk, Wkb, Wv, Wvb, dist, qf, kf, vt, dT);
    attn_kernel<<<dim3(64, 4), 1024, 0, stream>>>(query, dT, qf, kf, vt, fcw, fcb, d_out);
}